// Round 7
// baseline (11983.211 us; speedup 1.0000x reference)
//
#include <hip/hip_runtime.h>
#include <hip/hip_cooperative_groups.h>
#include <math.h>

#define BATCH 32
#define LEN   160000
#define NFFT  512
#define NT    626
#define NF    257
#define NFP   288          // NF padded to 9*32
#define HID   512
#define PROJN 5140
#define TC    32
#define NCHUNK 20
#define K0    800          // NFP + HID
#define K1    1024         // HID + HID
#define NBLK  64           // LSTM grid

typedef unsigned short ushort;
typedef __attribute__((ext_vector_type(8))) short short8;
typedef __attribute__((ext_vector_type(4))) float f32x4;

union U16 { short8 s8; unsigned long long q[2]; };

__device__ __forceinline__ float sigm(float x){ return 1.0f/(1.0f+expf(-x)); }
__device__ __forceinline__ ushort f2bf(float f){
  union{float f;unsigned u;} v; v.f=f;
  unsigned r = v.u + 0x7fffu + ((v.u>>16)&1u);
  return (ushort)(r>>16);
}

// ---------------- init: twiddles + zero int region ----------------
__global__ __launch_bounds__(256) void k_init(float* tw, int* zr, int nz){
  int i = blockIdx.x*256 + threadIdx.x;
  if (i < 512){
    float ang = 6.28318530717958647692f * (float)i / 512.0f;
    tw[i]     = cosf(ang);
    tw[512+i] = sinf(ang);
  }
  for (int j = i; j < nz; j += gridDim.x*256) zr[j] = 0;
}

__global__ __launch_bounds__(256) void k_zero(float* p, int n){
  for (int i = blockIdx.x*256 + threadIdx.x; i < n; i += gridDim.x*256) p[i] = 0.f;
}

// ---------------- prep: bf16 weight concat + combined biases + bf16 projW ----------------
__global__ __launch_bounds__(256) void k_prep(const float* __restrict__ Wih0, const float* __restrict__ Whh0,
                                              const float* __restrict__ bih0, const float* __restrict__ bhh0,
                                              const float* __restrict__ Wih1, const float* __restrict__ Whh1,
                                              const float* __restrict__ bih1, const float* __restrict__ bhh1,
                                              const float* __restrict__ projW,
                                              ushort* __restrict__ W0, ushort* __restrict__ W1,
                                              float* __restrict__ b0c, float* __restrict__ b1c,
                                              ushort* __restrict__ projWb){
  const int n0 = 2048*K0, n1 = 2048*K1, n2 = PROJN*HID;
  for (int i = blockIdx.x*256 + threadIdx.x; i < n0 + n1 + 4096 + n2; i += gridDim.x*256){
    if (i < n0){
      int r = i / K0, c = i - r*K0;
      float v = (c < 257) ? Wih0[(size_t)r*257 + c] : (c < NFP ? 0.f : Whh0[(size_t)r*512 + (c-NFP)]);
      W0[i] = f2bf(v);
    } else if (i < n0 + n1){
      int j = i - n0;
      int r = j / K1, c = j - r*K1;
      float v = (c < 512) ? Wih1[(size_t)r*512 + c] : Whh1[(size_t)r*512 + (c-512)];
      W1[j] = f2bf(v);
    } else if (i < n0 + n1 + 4096){
      int j = i - n0 - n1;
      if (j < 2048) b0c[j] = bih0[j] + bhh0[j];
      else          b1c[j-2048] = bih1[j-2048] + bhh1[j-2048];
    } else {
      int j = i - n0 - n1 - 4096;
      projWb[j] = f2bf(projW[j]);
    }
  }
}

// ---------------- fused STFT + mag^0.5 + LayerNorm -> bf16 padded [t][b][NFP] ----------------
// DFT via 4 independent rotators (table-exact init, 4x shorter dep chains).
__global__ __launch_bounds__(256) void k_stftln(const float* __restrict__ x, const float* __restrict__ tw,
                                                const float* __restrict__ g, const float* __restrict__ be,
                                                ushort* __restrict__ hlnb){
  int b = blockIdx.x / NT;
  int t = blockIdx.x % NT;
  __shared__ float fr[NFFT], mg[NF];
  __shared__ float red[16];
  const float* xb = x + (size_t)b*LEN;
  for (int n = threadIdx.x; n < NFFT; n += 256){
    int j = t*256 + n - 256;
    if (j < 0) j = -j;
    else if (j >= LEN) j = 2*LEN - 2 - j;
    fr[n] = xb[j] * (0.5f - 0.5f*tw[n]);
  }
  __syncthreads();
  float v=0.f, v2=0.f;
  for (int f = threadIdx.x; f < NF; f += 256){
    float c4 = tw[(4*f)&511], s4 = tw[512+((4*f)&511)];
    float cr0=1.f,            si0=0.f;
    float cr1=tw[f&511],      si1=tw[512+(f&511)];
    float cr2=tw[(2*f)&511],  si2=tw[512+((2*f)&511)];
    float cr3=tw[(3*f)&511],  si3=tw[512+((3*f)&511)];
    float ar0=0.f,ai0=0.f,ar1=0.f,ai1=0.f,ar2=0.f,ai2=0.f,ar3=0.f,ai3=0.f;
    #pragma unroll 4
    for (int n = 0; n < NFFT; n += 4){
      ar0 += fr[n  ]*cr0; ai0 -= fr[n  ]*si0;
      ar1 += fr[n+1]*cr1; ai1 -= fr[n+1]*si1;
      ar2 += fr[n+2]*cr2; ai2 -= fr[n+2]*si2;
      ar3 += fr[n+3]*cr3; ai3 -= fr[n+3]*si3;
      float tc, ts;
      tc = cr0*c4 - si0*s4; ts = cr0*s4 + si0*c4; cr0=tc; si0=ts;
      tc = cr1*c4 - si1*s4; ts = cr1*s4 + si1*c4; cr1=tc; si1=ts;
      tc = cr2*c4 - si2*s4; ts = cr2*s4 + si2*c4; cr2=tc; si2=ts;
      tc = cr3*c4 - si3*s4; ts = cr3*s4 + si3*c4; cr3=tc; si3=ts;
    }
    float ar = (ar0+ar1)+(ar2+ar3);
    float ai = (ai0+ai1)+(ai2+ai3);
    float m = sqrtf(sqrtf(ar*ar + ai*ai));
    mg[f]=m; v+=m; v2+=m*m;
  }
  for (int off=32; off; off>>=1){ v += __shfl_down(v,off); v2 += __shfl_down(v2,off); }
  int w = threadIdx.x >> 6;
  if ((threadIdx.x & 63)==0){ red[w]=v; red[8+w]=v2; }
  __syncthreads();
  if (threadIdx.x==0){
    float s  = red[0]+red[1]+red[2]+red[3];
    float s2 = red[8]+red[9]+red[10]+red[11];
    float mu = s/(float)NF;
    red[4]=mu;
    red[5]=rsqrtf(s2/(float)NF - mu*mu + 1e-5f);
  }
  __syncthreads();
  float mu=red[4], rs=red[5];
  size_t ob = ((size_t)t*BATCH + b)*NFP;
  for (int f=threadIdx.x; f<NFP; f+=256){
    float val = 0.f;
    if (f < NF) val = (mg[f]-mu)*rs*g[f] + be[f];
    hlnb[ob+f] = f2bf(val);
  }
}

// ---------------- persistent LSTM: write-through MALL exchange, no L2 wb/inv ----------------
// h0u: [2][32][256] uints (h0 ring, bf16-pairs). h1u: [(NT+1)][32][256] uints (h1 history ring).
// All cross-block h traffic via device-scope RELAXED atomics (bypass L2 -> MALL).
// Barrier: per-block flag slot store (RELAXED, after __syncthreads vmcnt drain) + 64-lane gather poll.
__global__ __launch_bounds__(256, 1) void k_lstm(const ushort* __restrict__ hlnb,
    const ushort* __restrict__ W0g, const ushort* __restrict__ W1g,
    const float* __restrict__ b0c, const float* __restrict__ b1c,
    unsigned* __restrict__ h0u, unsigned* __restrict__ h1u, unsigned* __restrict__ flags){
  __shared__ ushort Wlds0[32*808];   // rows padded 800->808
  __shared__ ushort Wlds1[32*1032];  // 1024->1032
  __shared__ float pc0[32][33];
  __shared__ float pc1[32][33];
  __shared__ ushort hsh0[32][8];
  __shared__ ushort hsh1[32][8];

  const int tid  = threadIdx.x;
  const int bid  = blockIdx.x;
  const int u0   = bid << 3;
  const int wave = tid >> 6;
  const int lane = tid & 63;
  const int col  = lane & 15;
  const int kg   = lane >> 4;
  const int mh   = wave & 1;
  const int nh   = wave >> 1;
  const int arow = (mh<<4) + col;          // batch row for A-frag
  const int nlo  = (nh<<4) + col;          // local gate-row for B-frag

  for (int v = tid; v < 3200; v += 256){
    int r = v/100, c8 = v - r*100;
    int grow = ((r>>3)<<9) + u0 + (r&7);
    *(short8*)&Wlds0[r*808 + c8*8] = *(const short8*)(W0g + (size_t)grow*K0 + c8*8);
  }
  for (int v = tid; v < 4096; v += 256){
    int r = v>>7, c8 = v&127;
    int grow = ((r>>3)<<9) + u0 + (r&7);
    *(short8*)&Wlds1[r*1032 + c8*8] = *(const short8*)(W1g + (size_t)grow*K1 + c8*8);
  }
  const int bb = tid & 31;
  const int ul = tid >> 5;
  const int u  = u0 + ul;
  float bc0r[4], bc1r[4];
  #pragma unroll
  for (int g=0; g<4; g++){ bc0r[g] = b0c[(g<<9)+u]; bc1r[g] = b1c[(g<<9)+u]; }
  float c0r = 0.f, c1r = 0.f;
  const ushort* wb0 = &Wlds0[nlo*808];
  const ushort* wb1 = &Wlds1[nlo*1032];
  const unsigned long long* h0q = (const unsigned long long*)h0u;
  const unsigned long long* h1q = (const unsigned long long*)h1u;
  __syncthreads();

  // prefetch x-part of layer0 for t=0 (plain loads; L2 stays warm all kernel)
  f32x4 acc0x = {0.f,0.f,0.f,0.f};
  {
    const ushort* xt = hlnb;
    #pragma unroll
    for (int kt=0; kt<9; kt++){
      short8 a = *(const short8*)(xt + arow*NFP + kt*32 + kg*8);
      short8 b = *(const short8*)(wb0 + kt*32 + kg*8);
      acc0x = __builtin_amdgcn_mfma_f32_16x16x32_bf16(a, b, acc0x, 0, 0, 0);
    }
  }

  for (int t = 0; t <= NT; ++t){
    const size_t h0base = ((size_t)((t-1)&1)*32 + arow)*128;   // u64 units
    f32x4 acc0 = acc0x;
    f32x4 acc1 = {0.f,0.f,0.f,0.f};
    if (t >= 1){                           // layer1, tau = t-1; reads h0(t-1), h1(t-2)=h1u[t-1]
      const size_t h1base = ((size_t)(t-1)*32 + arow)*128;
      #pragma unroll
      for (int kt=0; kt<16; kt++){
        U16 a;
        a.q[0] = __hip_atomic_load(h0q + h0base + kt*8 + kg*2,     __ATOMIC_RELAXED, __HIP_MEMORY_SCOPE_AGENT);
        a.q[1] = __hip_atomic_load(h0q + h0base + kt*8 + kg*2 + 1, __ATOMIC_RELAXED, __HIP_MEMORY_SCOPE_AGENT);
        short8 b = *(const short8*)(wb1 + kt*32 + kg*8);
        acc1 = __builtin_amdgcn_mfma_f32_16x16x32_bf16(a.s8, b, acc1, 0, 0, 0);
      }
      #pragma unroll
      for (int kt=0; kt<16; kt++){
        U16 a;
        a.q[0] = __hip_atomic_load(h1q + h1base + kt*8 + kg*2,     __ATOMIC_RELAXED, __HIP_MEMORY_SCOPE_AGENT);
        a.q[1] = __hip_atomic_load(h1q + h1base + kt*8 + kg*2 + 1, __ATOMIC_RELAXED, __HIP_MEMORY_SCOPE_AGENT);
        short8 b = *(const short8*)(wb1 + 512 + kt*32 + kg*8);
        acc1 = __builtin_amdgcn_mfma_f32_16x16x32_bf16(a.s8, b, acc1, 0, 0, 0);
      }
    }
    if (t < NT){                           // layer0 h-part, step t: reads h0(t-1)
      #pragma unroll
      for (int kt=0; kt<16; kt++){
        U16 a;
        a.q[0] = __hip_atomic_load(h0q + h0base + kt*8 + kg*2,     __ATOMIC_RELAXED, __HIP_MEMORY_SCOPE_AGENT);
        a.q[1] = __hip_atomic_load(h0q + h0base + kt*8 + kg*2 + 1, __ATOMIC_RELAXED, __HIP_MEMORY_SCOPE_AGENT);
        short8 b = *(const short8*)(wb0 + 288 + kt*32 + kg*8);
        acc0 = __builtin_amdgcn_mfma_f32_16x16x32_bf16(a.s8, b, acc0, 0, 0, 0);
      }
    }
    if (t < NT){
      #pragma unroll
      for (int j=0;j<4;j++) pc0[(mh<<4)+(kg<<2)+j][nlo] = acc0[j];
    }
    if (t >= 1){
      #pragma unroll
      for (int j=0;j<4;j++) pc1[(mh<<4)+(kg<<2)+j][nlo] = acc1[j];
    }
    __syncthreads();
    // ---- gate phase -> LDS ----
    if (t < NT){
      float p0 = pc0[bb][0*8+ul] + bc0r[0];
      float p1 = pc0[bb][1*8+ul] + bc0r[1];
      float p2 = pc0[bb][2*8+ul] + bc0r[2];
      float p3 = pc0[bb][3*8+ul] + bc0r[3];
      float cn = sigm(p1)*c0r + sigm(p0)*tanhf(p2);
      float hn = sigm(p3)*tanhf(cn);
      c0r = cn;
      hsh0[bb][ul] = f2bf(hn);
    }
    if (t >= 1){
      float p0 = pc1[bb][0*8+ul] + bc1r[0];
      float p1 = pc1[bb][1*8+ul] + bc1r[1];
      float p2 = pc1[bb][2*8+ul] + bc1r[2];
      float p3 = pc1[bb][3*8+ul] + bc1r[3];
      float cn = sigm(p1)*c1r + sigm(p0)*tanhf(p2);
      float hn = sigm(p3)*tanhf(cn);
      c1r = cn;
      hsh1[bb][ul] = f2bf(hn);
    }
    __syncthreads();
    // ---- pack + write-through store to MALL ----
    if (tid < 128){
      if (t < NT){
        int row = tid >> 2, q = tid & 3;
        unsigned v = (unsigned)hsh0[row][q*2] | ((unsigned)hsh0[row][q*2+1] << 16);
        __hip_atomic_store(&h0u[((size_t)(t&1)*32 + row)*256 + (u0>>1) + q], v,
                           __ATOMIC_RELAXED, __HIP_MEMORY_SCOPE_AGENT);
      }
    } else {
      if (t >= 1){
        int t2 = tid - 128; int row = t2 >> 2, q = t2 & 3;
        unsigned v = (unsigned)hsh1[row][q*2] | ((unsigned)hsh1[row][q*2+1] << 16);
        __hip_atomic_store(&h1u[((size_t)t*32 + row)*256 + (u0>>1) + q], v,
                           __ATOMIC_RELAXED, __HIP_MEMORY_SCOPE_AGENT);
      }
    }
    __syncthreads();                       // compiler emits vmcnt(0) drain before s_barrier
    if (tid == 0)                          // arrive (own line; stores already at MALL)
      __hip_atomic_store(&flags[bid*32], (unsigned)(t+1), __ATOMIC_RELAXED, __HIP_MEMORY_SCOPE_AGENT);
    // overlap: h-independent x-part of layer0 for step t+1
    acc0x = f32x4{0.f,0.f,0.f,0.f};
    if (t+1 < NT){
      const ushort* xt = hlnb + (size_t)(t+1)*BATCH*NFP;
      #pragma unroll
      for (int kt=0; kt<9; kt++){
        short8 a = *(const short8*)(xt + arow*NFP + kt*32 + kg*8);
        short8 b = *(const short8*)(wb0 + kt*32 + kg*8);
        acc0x = __builtin_amdgcn_mfma_f32_16x16x32_bf16(a, b, acc0x, 0, 0, 0);
      }
    }
    if (wave == 0){                        // 64-lane gather poll, relaxed
      unsigned tgt = (unsigned)(t+1);
      while (true){
        unsigned v = __hip_atomic_load(&flags[lane*32], __ATOMIC_RELAXED, __HIP_MEMORY_SCOPE_AGENT);
        if (__all(v >= tgt)) break;
        __builtin_amdgcn_s_sleep(1);
      }
    }
    asm volatile("" ::: "memory");
    __syncthreads();
  }
}

// ---------------- STFT for a tail chunk (4-rotator DFT) ----------------
__global__ __launch_bounds__(256) void k_stft_chunk(const float* __restrict__ x, const float* __restrict__ tw,
                                                    float* __restrict__ spR, float* __restrict__ spI, int tb0){
  int tt = blockIdx.x;
  int b  = blockIdx.y;
  int t  = tb0 + tt;
  if (t < 0 || t >= NT){
    for (int f = threadIdx.x; f < NF; f += 256){
      size_t o = ((size_t)b*NF + f)*36 + tt;
      spR[o]=0.f; spI[o]=0.f;
    }
    return;
  }
  __shared__ float fr[NFFT];
  const float* xb = x + (size_t)b*LEN;
  for (int n = threadIdx.x; n < NFFT; n += 256){
    int j = t*256 + n - 256;
    if (j < 0) j = -j;
    else if (j >= LEN) j = 2*LEN - 2 - j;
    fr[n] = xb[j] * (0.5f - 0.5f*tw[n]);
  }
  __syncthreads();
  for (int f = threadIdx.x; f < NF; f += 256){
    float c4 = tw[(4*f)&511], s4 = tw[512+((4*f)&511)];
    float cr0=1.f,            si0=0.f;
    float cr1=tw[f&511],      si1=tw[512+(f&511)];
    float cr2=tw[(2*f)&511],  si2=tw[512+((2*f)&511)];
    float cr3=tw[(3*f)&511],  si3=tw[512+((3*f)&511)];
    float ar0=0.f,ai0=0.f,ar1=0.f,ai1=0.f,ar2=0.f,ai2=0.f,ar3=0.f,ai3=0.f;
    #pragma unroll 4
    for (int n = 0; n < NFFT; n += 4){
      ar0 += fr[n  ]*cr0; ai0 -= fr[n  ]*si0;
      ar1 += fr[n+1]*cr1; ai1 -= fr[n+1]*si1;
      ar2 += fr[n+2]*cr2; ai2 -= fr[n+2]*si2;
      ar3 += fr[n+3]*cr3; ai3 -= fr[n+3]*si3;
      float tc, ts;
      tc = cr0*c4 - si0*s4; ts = cr0*s4 + si0*c4; cr0=tc; si0=ts;
      tc = cr1*c4 - si1*s4; ts = cr1*s4 + si1*c4; cr1=tc; si1=ts;
      tc = cr2*c4 - si2*s4; ts = cr2*s4 + si2*c4; cr2=tc; si2=ts;
      tc = cr3*c4 - si3*s4; ts = cr3*s4 + si3*c4; cr3=tc; si3=ts;
    }
    size_t o = ((size_t)b*NF + f)*36 + tt;
    spR[o] = (ar0+ar1)+(ar2+ar3);
    spI[o] = (ai0+ai1)+(ai2+ai3);
  }
}

// ---------------- MFMA GEMM: C[M,N] = A_bf16[M,512] * Bb_bf16[N,512]^T + bias, tanh ----------------
__global__ __launch_bounds__(256) void k_gemm_mfma(const ushort* __restrict__ A, const ushort* __restrict__ Bb,
                                                   const float* __restrict__ bias,
                                                   float* __restrict__ C, int M, int N){
  int bm = blockIdx.y*64, bn = blockIdx.x*64;
  int wave = threadIdx.x >> 6, lane = threadIdx.x & 63;
  int wm = wave >> 1, wn = wave & 1;
  int col = lane & 15, kg = lane >> 4;
  f32x4 acc00={0.f,0.f,0.f,0.f}, acc01=acc00, acc10=acc00, acc11=acc00;
  const ushort* Ap = A + (size_t)(bm + wm*32)*512;
  int nr0 = bn + wn*32 + col;
  int nr1 = nr0 + 16;
  const ushort* Bp0 = Bb + (size_t)((nr0<N)?nr0:0)*512;
  const ushort* Bp1 = Bb + (size_t)((nr1<N)?nr1:0)*512;
  #pragma unroll 4
  for (int k0=0; k0<512; k0+=32){
    short8 a0 = *(const short8*)(Ap + (size_t)col*512 + k0 + kg*8);
    short8 a1 = *(const short8*)(Ap + (size_t)(16+col)*512 + k0 + kg*8);
    short8 b0 = *(const short8*)(Bp0 + k0 + kg*8);
    short8 b1 = *(const short8*)(Bp1 + k0 + kg*8);
    acc00 = __builtin_amdgcn_mfma_f32_16x16x32_bf16(a0, b0, acc00, 0, 0, 0);
    acc01 = __builtin_amdgcn_mfma_f32_16x16x32_bf16(a0, b1, acc01, 0, 0, 0);
    acc10 = __builtin_amdgcn_mfma_f32_16x16x32_bf16(a1, b0, acc10, 0, 0, 0);
    acc11 = __builtin_amdgcn_mfma_f32_16x16x32_bf16(a1, b1, acc11, 0, 0, 0);
  }
  #define STORE_ACC(ACC, MI, NI) { \
    int n = bn + wn*32 + (NI)*16 + col; \
    if (n < N){ \
      float bv = bias[n]; \
      _Pragma("unroll") \
      for (int j=0;j<4;j++){ \
        int m = bm + wm*32 + (MI)*16 + kg*4 + j; \
        C[(size_t)m*N + n] = tanhf(ACC[j] + bv); \
      } \
    } }
  STORE_ACC(acc00, 0, 0)
  STORE_ACC(acc01, 0, 1)
  STORE_ACC(acc10, 1, 0)
  STORE_ACC(acc11, 1, 1)
  #undef STORE_ACC
}

// ---------------- fused deep-filter + irfft(4-rotator) + window + OLA(atomic) ----------------
__global__ __launch_bounds__(256) void k_ifused(const float* __restrict__ prch,
    const float* __restrict__ spR, const float* __restrict__ spI,
    const float* __restrict__ tw, float* __restrict__ out, int tb0){
  int tl = blockIdx.x >> 6;
  int b  = (blockIdx.x >> 1) & 31;
  int s  = blockIdx.x & 1;
  int tau = tb0 + 4 + tl;
  __shared__ float re[NF], im[NF];
  const float* p = prch + ((size_t)tl*BATCH + b)*PROJN;
  for (int f=threadIdx.x; f<NF; f+=256){
    float ar=0.f, ai=0.f;
    size_t so = ((size_t)b*NF + f)*36;
    #pragma unroll
    for (int d=0; d<5; d++){
      int ts = tb0 + tl + d;
      if (ts >= 0){
        float sr=spR[so + tl + d], si=spI[so + tl + d];
        float cr=p[d*514 + s*257 + f];
        float ci=p[2570 + d*514 + s*257 + f];
        ar += sr*cr - si*ci;
        ai += sr*ci + si*cr;
      }
    }
    re[f]=ar; im[f]=ai;
  }
  __syncthreads();
  float* ob = out + (size_t)(b*2+s)*LEN;
  for (int n=threadIdx.x; n<NFFT; n+=256){
    float c4 = tw[(4*n)&511], s4 = tw[512+((4*n)&511)];
    float crA=tw[n&511],     siA=tw[512+(n&511)];      // k=1
    float crB=tw[(2*n)&511], siB=tw[512+((2*n)&511)];  // k=2
    float crC=tw[(3*n)&511], siC=tw[512+((3*n)&511)];  // k=3
    float crD=c4,            siD=s4;                   // k=4
    float a0=0.f,a1=0.f,a2=0.f,a3=0.f;
    #pragma unroll 4
    for (int m=0; m<63; m++){
      int k = 4*m+1;
      a0 += re[k  ]*crA - im[k  ]*siA;
      a1 += re[k+1]*crB - im[k+1]*siB;
      a2 += re[k+2]*crC - im[k+2]*siC;
      a3 += re[k+3]*crD - im[k+3]*siD;
      float tc, ts;
      tc = crA*c4 - siA*s4; ts = crA*s4 + siA*c4; crA=tc; siA=ts;
      tc = crB*c4 - siB*s4; ts = crB*s4 + siB*c4; crB=tc; siB=ts;
      tc = crC*c4 - siC*s4; ts = crC*s4 + siC*c4; crC=tc; siC=ts;
      tc = crD*c4 - siD*s4; ts = crD*s4 + siD*c4; crD=tc; siD=ts;
    }
    a0 += re[253]*crA - im[253]*siA;
    a1 += re[254]*crB - im[254]*siB;
    a2 += re[255]*crC - im[255]*siC;
    float acc = re[0] + ((n&1) ? -re[256] : re[256]) + 2.f*((a0+a1)+(a2+a3));
    int pos = tau*256 - 256 + n;
    if (pos >= 0 && pos < LEN)
      atomicAdd(ob + pos, acc * (1.0f/512.0f) * (0.5f - 0.5f*tw[n&511]));
  }
}

// ---------------- normalize by wsq ----------------
__global__ __launch_bounds__(256) void k_norm(float* __restrict__ out, const float* __restrict__ tw, int n){
  for (int i = blockIdx.x*256 + threadIdx.x; i < n; i += gridDim.x*256){
    int m = (i % LEN) & 255;
    float cm = tw[m];
    float w1 = 0.5f - 0.5f*cm;
    float w2 = 0.5f + 0.5f*cm;
    out[i] = out[i] / (w1*w1 + w2*w2);
  }
}

extern "C" void kernel_launch(void* const* d_in, const int* in_sizes, int n_in,
                              void* d_out, int out_size, void* d_ws, size_t ws_size,
                              hipStream_t stream){
  const float* x     = (const float*)d_in[0];
  const float* ln_g  = (const float*)d_in[1];
  const float* ln_b  = (const float*)d_in[2];
  const float* Wih0  = (const float*)d_in[3];
  const float* Whh0  = (const float*)d_in[4];
  const float* bih0  = (const float*)d_in[5];
  const float* bhh0  = (const float*)d_in[6];
  const float* Wih1  = (const float*)d_in[7];
  const float* Whh1  = (const float*)d_in[8];
  const float* bih1  = (const float*)d_in[9];
  const float* bhh1  = (const float*)d_in[10];
  const float* projW = (const float*)d_in[11];
  const float* projb = (const float*)d_in[12];

  char* base = (char*)d_ws;
  size_t off = 0;
  auto carve = [&](size_t bytes)->char*{
    char* p = base + off;
    off += (bytes + 255) & ~(size_t)255;
    return p;
  };
  float*  tw     = (float*) carve(1024*4);
  ushort* hlnb   = (ushort*)carve((size_t)NT*BATCH*NFP*2);
  ushort* W0     = (ushort*)carve((size_t)2048*K0*2);
  ushort* W1     = (ushort*)carve((size_t)2048*K1*2);
  float*  b0c    = (float*) carve(2048*4);
  float*  b1c    = (float*) carve(2048*4);
  ushort* projWb = (ushort*)carve((size_t)PROJN*HID*2);
  unsigned* h0u  = (unsigned*)carve((size_t)2*BATCH*256*4);      // 65536B
  unsigned* flags= (unsigned*)carve(NBLK*32*4);                  // 8192B (contiguous after h0u)
  unsigned* h1u  = (unsigned*)carve((size_t)(NT+1)*BATCH*256*4); // h1 history ring (bf16 pairs)
  float*  spR    = (float*) carve((size_t)BATCH*NF*36*4);
  float*  spI    = (float*) carve((size_t)BATCH*NF*36*4);
  float*  prch   = (float*) carve((size_t)TC*BATCH*PROJN*4);

  int nzInts = (65536 + NBLK*32*4) / 4;    // h0u + flags

  k_init<<<512, 256, 0, stream>>>(tw, (int*)h0u, nzInts);
  k_zero<<<64, 256, 0, stream>>>((float*)h1u, BATCH*256);        // zero slot 0 (h1(-1))
  k_zero<<<2048, 256, 0, stream>>>((float*)d_out, out_size);
  k_prep<<<4096, 256, 0, stream>>>(Wih0, Whh0, bih0, bhh0, Wih1, Whh1, bih1, bhh1,
                                   projW, W0, W1, b0c, b1c, projWb);
  k_stftln<<<BATCH*NT, 256, 0, stream>>>(x, tw, ln_g, ln_b, hlnb);

  {
    void* args[] = { (void*)&hlnb, (void*)&W0, (void*)&W1, (void*)&b0c, (void*)&b1c,
                     (void*)&h0u, (void*)&h1u, (void*)&flags };
    hipLaunchCooperativeKernel(reinterpret_cast<void*>(k_lstm), dim3(NBLK), dim3(256),
                               args, 0, stream);
  }

  for (int c = 0; c < NCHUNK; ++c){
    int tb0 = c*TC - 4;
    int tcc = (c == NCHUNK-1) ? (NT - c*TC) : TC;
    k_stft_chunk<<<dim3(36, BATCH), 256, 0, stream>>>(x, tw, spR, spI, tb0);
    dim3 gp((PROJN+63)/64, (tcc*BATCH)/64);
    k_gemm_mfma<<<gp, 256, 0, stream>>>((const ushort*)h1u + ((size_t)(c*TC)+1)*BATCH*HID,
                                        projWb, projb, prch, tcc*BATCH, PROJN);
    k_ifused<<<tcc*64, 256, 0, stream>>>(prch, spR, spI, tw, (float*)d_out, tb0);
  }

  k_norm<<<2048, 256, 0, stream>>>((float*)d_out, tw, out_size);
}